// Round 10
// baseline (246.926 us; speedup 1.0000x reference)
//
#include <hip/hip_runtime.h>
#include <math.h>

#define NN 50000
#define NE 1000000
#define EC 31            // edge chunks, chunk = e >> CSH (31*32768 >= NE)
#define ECP 32           // rpre per-node stride (bytes)
#define CSH 15           // chunk size 32768
#define WR 8             // counter ranges
#define RNG 6250         // counters per range (8*6250 = NN)
#define RPAD 6272        // padded dump stride (ints), block-exclusive regions
#define NCNT (EC * WR)   // 248 count blocks
#define NPB 24           // prep blocks (24*1024 = 24576 = 64*320+64*64)
#define NGB 782          // gemm L1 blocks: ceil(NN/64)
#define NSB 196          // scan1 blocks (196*256 >= NN)

typedef __bf16 bf16x8 __attribute__((ext_vector_type(8)));
typedef float f32x4 __attribute__((ext_vector_type(4)));

__device__ inline unsigned short f2bf(float f) {          // fp32 -> bf16 RNE
    unsigned u = __float_as_uint(f);
    u += 0x7FFFu + ((u >> 16) & 1u);
    return (unsigned short)(u >> 16);
}
__device__ inline float bf2f(unsigned short s) {
    return __uint_as_float(((unsigned)s) << 16);
}
__device__ inline float bflo(unsigned r) { return __uint_as_float(r << 16); }
__device__ inline float bfhi(unsigned r) { return __uint_as_float(r & 0xffff0000u); }
__device__ inline unsigned cvtpk(float lo, float hi) {    // 2xf32 -> packed bf16 (RNE)
    unsigned u;
    asm("v_cvt_pk_bf16_f32 %0, %1, %2" : "=v"(u) : "v"(lo), "v"(hi));
    return u;
}

// ---- FUSED: CSR count (blocks [0,NCNT)) + weight prep (tail blocks). ----
__global__ __launch_bounds__(1024) void k_count_prep(
        const int* __restrict__ ei, int* __restrict__ cnt,
        unsigned char* __restrict__ pos,
        const float* __restrict__ W1, const float* __restrict__ W2,
        unsigned short* __restrict__ Bt1, unsigned short* __restrict__ Bt2)
{
    __shared__ __align__(16) int sm[RNG];          // 25000B (count blocks only)
    const int tid = threadIdx.x;
    const int bid = blockIdx.x;

    if (bid >= NCNT) {                             // ---- prep body ----
        int t = (bid - NCNT) * 1024 + tid;
        if (t < 64 * 320) {
            int c = t / 320, k = t % 320;
            Bt1[t] = (k < 300) ? f2bf(W1[k * 64 + c]) : (unsigned short)0;
        } else {
            int i = t - 64 * 320;
            int c = i >> 6, k = i & 63;
            Bt2[i] = f2bf(W2[k * 64 + c]);
        }
        return;
    }
    // ---- count body: chunk c, range w ----
    const int c = bid >> 3, w = bid & 7;
    const int lo = w * RNG;
    for (int j = tid; j < RNG; j += 1024) sm[j] = 0;
    __syncthreads();
    const int base = c << CSH;
    #pragma unroll
    for (int it = 0; it < (1 << CSH) / 4096; ++it) {
        int e = base + (it * 1024 + tid) * 4;
        if (e < NE) {                               // NE%4==0 -> whole int4 valid
            int4 d = *(const int4*)(ei + NE + e);
            unsigned t0 = (unsigned)(d.x - lo), t1 = (unsigned)(d.y - lo);
            unsigned t2 = (unsigned)(d.z - lo), t3 = (unsigned)(d.w - lo);
            if (t0 < RNG) pos[e]     = (unsigned char)atomicAdd(&sm[t0], 1);
            if (t1 < RNG) pos[e + 1] = (unsigned char)atomicAdd(&sm[t1], 1);
            if (t2 < RNG) pos[e + 2] = (unsigned char)atomicAdd(&sm[t2], 1);
            if (t3 < RNG) pos[e + 3] = (unsigned char)atomicAdd(&sm[t3], 1);
        }
    }
    __syncthreads();
    int* dstp = cnt + (size_t)bid * RPAD;          // exclusive region
    for (int j = tid; j < RNG; j += 1024) dstp[j] = sm[j];
}

// ---- FUSED: L1 MFMA GEMM (blocks [0,NGB)) + scan1 (tail blocks).
//      Staging fp32->bf16 now via v_cvt_pk_bf16_f32 (1 inst per pair vs ~8
//      scalar RNE ops) -- the staging VALU was the GEMM's real cost
//      (MfmaUtil ~1%, staging-dominated). ----
__global__ __launch_bounds__(256) void k_gemm_scan(
        const float* __restrict__ A, const unsigned short* __restrict__ Bt,
        unsigned short* __restrict__ hb,
        const float* __restrict__ asrc, const float* __restrict__ adst,
        float* __restrict__ ss, float* __restrict__ sd,
        const int* __restrict__ cnt, int* __restrict__ excl,
        int* __restrict__ sums, unsigned char* __restrict__ rpre)
{
    __shared__ __align__(16) unsigned short lds[9216];   // 18432B
    const int tid = threadIdx.x;
    const int bid = blockIdx.x;

    if (bid >= NGB) {
        // ---------------- scan1 body (256 elements/block) ----------------
        const int sb = bid - NGB;
        int i = sb * 256 + tid;
        int v = 0;
        if (i < NN) {
            int w8 = i / RNG;                    // counter range 0..7
            int j = i - w8 * RNG;
            int run = 0;
            unsigned pk[ECP / 4];
            #pragma unroll
            for (int q = 0; q < ECP / 4; ++q) pk[q] = 0;
            #pragma unroll
            for (int cc = 0; cc < EC; ++cc) {
                pk[cc >> 2] |= ((unsigned)run & 0xffu) << ((cc & 3) * 8);
                run += cnt[(size_t)(cc * 8 + w8) * RPAD + j];
            }
            v = run;
            *(uint4*)(rpre + (size_t)i * ECP)      = make_uint4(pk[0], pk[1], pk[2], pk[3]);
            *(uint4*)(rpre + (size_t)i * ECP + 16) = make_uint4(pk[4], pk[5], pk[6], pk[7]);
        }
        int* buf = (int*)lds;
        buf[tid] = v;
        __syncthreads();
        #pragma unroll
        for (int off = 1; off < 256; off <<= 1) {
            int t = (tid >= off) ? buf[tid - off] : 0;
            __syncthreads();
            buf[tid] += t;
            __syncthreads();
        }
        if (i < NN) excl[i] = buf[tid] - v;
        if (tid == 255) sums[sb] = buf[255];
        return;
    }

    // ---------------- gemm body (HEADS=8, A fp32, K=300, BK=64, KT=5) ----------------
    const int row0 = bid * 64;
    const int lane = tid & 63, w = tid >> 6;
    const int quad = lane >> 4, mm = lane & 15;
    const int sr = tid >> 2, q16 = (tid & 3) * 16;
    const int gsr = row0 + sr;
    const int K = 300, M = NN;

    f32x4 acc[4];
    #pragma unroll
    for (int i = 0; i < 4; ++i) acc[i] = (f32x4){0.f, 0.f, 0.f, 0.f};

    for (int kt = 0; kt < 5; ++kt) {
        const int k0 = kt * 64;
        int4 a0 = {0, 0, 0, 0}, a1 = {0, 0, 0, 0};
        if (gsr < M) {
            const float* ap = A + (size_t)gsr * K + k0 + q16;
            if (k0 + q16 + 15 < K) {
                float4 v0 = *(const float4*)ap;
                float4 v1 = *(const float4*)(ap + 4);
                float4 v2 = *(const float4*)(ap + 8);
                float4 v3 = *(const float4*)(ap + 12);
                a0.x = (int)cvtpk(v0.x, v0.y); a0.y = (int)cvtpk(v0.z, v0.w);
                a0.z = (int)cvtpk(v1.x, v1.y); a0.w = (int)cvtpk(v1.z, v1.w);
                a1.x = (int)cvtpk(v2.x, v2.y); a1.y = (int)cvtpk(v2.z, v2.w);
                a1.z = (int)cvtpk(v3.x, v3.y); a1.w = (int)cvtpk(v3.z, v3.w);
            } else {
                unsigned short* u0 = (unsigned short*)&a0;
                unsigned short* u1 = (unsigned short*)&a1;
                #pragma unroll
                for (int j = 0; j < 8; ++j)
                    u0[j] = (k0 + q16 + j < K) ? f2bf(ap[j]) : (unsigned short)0;
                #pragma unroll
                for (int j = 0; j < 8; ++j)
                    u1[j] = (k0 + q16 + 8 + j < K) ? f2bf(ap[8 + j]) : (unsigned short)0;
            }
        }
        *(int4*)(lds + sr * 72 + q16)     = a0;
        *(int4*)(lds + sr * 72 + q16 + 8) = a1;
        *(int4*)(lds + 4608 + sr * 72 + q16) =
            *(const int4*)(Bt + (size_t)sr * 320 + k0 + q16);
        *(int4*)(lds + 4608 + sr * 72 + q16 + 8) =
            *(const int4*)(Bt + (size_t)sr * 320 + k0 + q16 + 8);
        __syncthreads();
        bf16x8 af0 = *(const bf16x8*)(lds + (w * 16 + mm) * 72 + quad * 8);
        bf16x8 af1 = *(const bf16x8*)(lds + (w * 16 + mm) * 72 + 32 + quad * 8);
        #pragma unroll
        for (int nt = 0; nt < 4; ++nt) {
            bf16x8 b0 = *(const bf16x8*)(lds + 4608 + (nt * 16 + mm) * 72 + quad * 8);
            bf16x8 b1 = *(const bf16x8*)(lds + 4608 + (nt * 16 + mm) * 72 + 32 + quad * 8);
            acc[nt] = __builtin_amdgcn_mfma_f32_16x16x32_bf16(af0, b0, acc[nt], 0, 0, 0);
            acc[nt] = __builtin_amdgcn_mfma_f32_16x16x32_bf16(af1, b1, acc[nt], 0, 0, 0);
        }
        __syncthreads();
    }
    // epilogue: C (col=lane&15, row=quad*4+reg) -> LDS bf16 tile (stride 72)
    #pragma unroll
    for (int nt = 0; nt < 4; ++nt)
        #pragma unroll
        for (int reg = 0; reg < 4; ++reg)
            lds[w * 1152 + (quad * 4 + reg) * 72 + nt * 16 + mm] = f2bf(acc[nt][reg]);
    __syncthreads();
    const int cg = (tid & 3) * 16;
    const unsigned short* crow = lds + (sr >> 4) * 1152 + (sr & 15) * 72;
    if (gsr < M) {
        *(int4*)(hb + (size_t)gsr * 64 + cg)     = *(const int4*)(crow + cg);
        *(int4*)(hb + (size_t)gsr * 64 + cg + 8) = *(const int4*)(crow + cg + 8);
    }
    #pragma unroll
    for (int hh = 0; hh < 2; ++hh) {
        int hd = (tid & 3) + hh * 4;
        float pss = 0.f, psd = 0.f;
        #pragma unroll
        for (int c = 0; c < 8; ++c) {
            float hv = bf2f(crow[hd * 8 + c]);
            pss += hv * asrc[hd * 8 + c];
            psd += hv * adst[hd * 8 + c];
        }
        if (gsr < M) { ss[gsr * 8 + hd] = pss; sd[gsr * 8 + hd] = psd; }
    }
}

// ---- MFMA GEMM layer 2 (A bf16, K=64 single tile, 1 barrier pair) ----
__global__ __launch_bounds__(256) void gemm_l2(const unsigned short* __restrict__ A,
        const unsigned short* __restrict__ Bt, unsigned short* __restrict__ hb,
        const float* __restrict__ asrc, const float* __restrict__ adst,
        float* __restrict__ ss, float* __restrict__ sd)
{
    __shared__ __align__(16) unsigned short lds[9216];
    const int tid  = threadIdx.x;
    const int row0 = blockIdx.x * 64;
    const int lane = tid & 63, w = tid >> 6;
    const int quad = lane >> 4, mm = lane & 15;
    const int sr = tid >> 2, q16 = (tid & 3) * 16;
    const int gsr = row0 + sr;

    f32x4 acc[4];
    #pragma unroll
    for (int i = 0; i < 4; ++i) acc[i] = (f32x4){0.f, 0.f, 0.f, 0.f};

    int4 a0 = {0, 0, 0, 0}, a1 = {0, 0, 0, 0};
    if (gsr < NN) {
        a0 = *(const int4*)(A + (size_t)gsr * 64 + q16);
        a1 = *(const int4*)(A + (size_t)gsr * 64 + q16 + 8);
    }
    *(int4*)(lds + sr * 72 + q16)     = a0;
    *(int4*)(lds + sr * 72 + q16 + 8) = a1;
    *(int4*)(lds + 4608 + sr * 72 + q16)     = *(const int4*)(Bt + sr * 64 + q16);
    *(int4*)(lds + 4608 + sr * 72 + q16 + 8) = *(const int4*)(Bt + sr * 64 + q16 + 8);
    __syncthreads();
    bf16x8 af0 = *(const bf16x8*)(lds + (w * 16 + mm) * 72 + quad * 8);
    bf16x8 af1 = *(const bf16x8*)(lds + (w * 16 + mm) * 72 + 32 + quad * 8);
    #pragma unroll
    for (int nt = 0; nt < 4; ++nt) {
        bf16x8 b0 = *(const bf16x8*)(lds + 4608 + (nt * 16 + mm) * 72 + quad * 8);
        bf16x8 b1 = *(const bf16x8*)(lds + 4608 + (nt * 16 + mm) * 72 + 32 + quad * 8);
        acc[nt] = __builtin_amdgcn_mfma_f32_16x16x32_bf16(af0, b0, acc[nt], 0, 0, 0);
        acc[nt] = __builtin_amdgcn_mfma_f32_16x16x32_bf16(af1, b1, acc[nt], 0, 0, 0);
    }
    __syncthreads();
    #pragma unroll
    for (int nt = 0; nt < 4; ++nt)
        #pragma unroll
        for (int reg = 0; reg < 4; ++reg)
            lds[w * 1152 + (quad * 4 + reg) * 72 + nt * 16 + mm] = f2bf(acc[nt][reg]);
    __syncthreads();
    const int cg = (tid & 3) * 16;
    const unsigned short* crow = lds + (sr >> 4) * 1152 + (sr & 15) * 72;
    if (gsr < NN) {
        *(int4*)(hb + (size_t)gsr * 64 + cg)     = *(const int4*)(crow + cg);
        *(int4*)(hb + (size_t)gsr * 64 + cg + 8) = *(const int4*)(crow + cg + 8);
    }
    int p = tid & 3;
    float pss = 0.f, psd = 0.f;
    #pragma unroll
    for (int c = 0; c < 16; ++c) {
        float hv = bf2f(crow[p * 16 + c]);
        pss += hv * asrc[p * 16 + c];
        psd += hv * adst[p * 16 + c];
    }
    pss += __shfl_xor(pss, 1); psd += __shfl_xor(psd, 1);
    pss += __shfl_xor(pss, 2); psd += __shfl_xor(psd, 2);
    if (p == 0 && gsr < NN) { ss[gsr] = pss; sd[gsr] = psd; }
}

// ------------- scan stage 2+3: each block scans 196 sums redundantly -------------
__global__ __launch_bounds__(1024) void scan23(const int* __restrict__ excl,
        const int* __restrict__ sums, int* __restrict__ rowptr)
{
    int blk = (int)blockIdx.x * 4;                  // 1024-block spans 4 scan1 blocks
    int off = 0;
    for (int j = 0; j < blk; ++j) off += sums[j];   // uniform scalar loop
    int sub = (threadIdx.x >> 8);                   // which 256-group
    for (int j = 0; j < sub; ++j) off += sums[blk + j];
    int i = (int)blockIdx.x * 1024 + threadIdx.x;
    if (i < NN) rowptr[i] = excl[i] + off;
    if (i == 0) rowptr[NN] = NE;
}

// ------ CSR scatter: slot = rowptr[d] + rpre[d][chunk(e)] + pos[e] ------
__global__ __launch_bounds__(256) void scatter_k(const int* __restrict__ ei,
        const int* __restrict__ rowptr, const unsigned char* __restrict__ pos,
        const unsigned char* __restrict__ rpre, unsigned short* __restrict__ col)
{
    int e = (blockIdx.x * 256 + threadIdx.x) * 4;   // NE % 4 == 0
    if (e >= NE) return;
    int c = e >> CSH;                               // chunk uniform over the int4
    int4 s = *(const int4*)(ei + e);
    int4 d = *(const int4*)(ei + NE + e);
    uchar4 p = *(const uchar4*)(pos + e);
    int r0 = rowptr[d.x] + (int)rpre[(d.x << 5) + c] + p.x;
    int r1 = rowptr[d.y] + (int)rpre[(d.y << 5) + c] + p.y;
    int r2 = rowptr[d.z] + (int)rpre[(d.z << 5) + c] + p.z;
    int r3 = rowptr[d.w] + (int)rpre[(d.w << 5) + c] + p.w;
    col[r0] = (unsigned short)s.x;
    col[r1] = (unsigned short)s.y;
    col[r2] = (unsigned short)s.z;
    col[r3] = (unsigned short)s.w;
}

#define LEAKY(s) ((s) > 0.f ? (s) : 0.2f * (s))

// ------- layer1 agg: 4 lanes/edge (16 slots). R3 PMC: VALUBusy 60% ->
//      VALU-bound, so cut per-edge ops: int4-pair loads (16B/lane), float2 ss
//      gather, exactly one exp per (edge,head) -- no redundant alpha math. -------
__global__ __launch_bounds__(256) void agg_l1(const int* __restrict__ rowptr,
        const unsigned short* __restrict__ col, const unsigned short* __restrict__ hb,
        const float* __restrict__ ss, const float* __restrict__ sd,
        const float* __restrict__ b, unsigned short* __restrict__ out)
{
    int n = (blockIdx.x * 256 + threadIdx.x) >> 6;
    int lane = threadIdx.x & 63;
    if (n >= NN) return;
    const int sl = lane >> 2;            // edge slot 0..15
    const int j  = lane & 3;             // channel quarter: ch [16j,16j+16)
    const int cb = j << 4;               // heads 2j, 2j+1
    float2 sdp = *(const float2*)(sd + n * 8 + j * 2);
    int r0 = rowptr[n], r1 = rowptr[n + 1];
    float acc[16];
    #pragma unroll
    for (int k = 0; k < 16; ++k) acc[k] = 0.f;
    float ds0 = 0.f, ds1 = 0.f;
    for (int i = r0; i < r1; i += 16) {
        int e = i + sl;
        bool v = e < r1;
        int a = (int)col[v ? e : r0];
        const unsigned short* hp = hb + a * 64 + cb;
        uint4 h0 = *(const uint4*)hp;            // ch cb..cb+7  (head 2j)
        uint4 h1 = *(const uint4*)(hp + 8);      // ch cb+8..+15 (head 2j+1)
        float2 ssp = *(const float2*)(ss + a * 8 + j * 2);
        float s0 = ssp.x + sdp.x, s1 = ssp.y + sdp.y;
        float w0 = v ? __expf(LEAKY(s0)) : 0.f;
        float w1 = v ? __expf(LEAKY(s1)) : 0.f;
        acc[0]  += w0 * bflo(h0.x); acc[1]  += w0 * bfhi(h0.x);
        acc[2]  += w0 * bflo(h0.y); acc[3]  += w0 * bfhi(h0.y);
        acc[4]  += w0 * bflo(h0.z); acc[5]  += w0 * bfhi(h0.z);
        acc[6]  += w0 * bflo(h0.w); acc[7]  += w0 * bfhi(h0.w);
        acc[8]  += w1 * bflo(h1.x); acc[9]  += w1 * bfhi(h1.x);
        acc[10] += w1 * bflo(h1.y); acc[11] += w1 * bfhi(h1.y);
        acc[12] += w1 * bflo(h1.z); acc[13] += w1 * bfhi(h1.z);
        acc[14] += w1 * bflo(h1.w); acc[15] += w1 * bfhi(h1.w);
        ds0 += w0; ds1 += w1;
    }
    #pragma unroll
    for (int m = 4; m <= 32; m <<= 1) {
        #pragma unroll
        for (int k = 0; k < 16; ++k) acc[k] += __shfl_xor(acc[k], m);
        ds0 += __shfl_xor(ds0, m);
        ds1 += __shfl_xor(ds1, m);
    }
    if (sl == 0) {
        float i0 = 1.f / (ds0 + 1e-16f);
        float i1 = 1.f / (ds1 + 1e-16f);
        float vo[16];
        #pragma unroll
        for (int k = 0; k < 8; ++k) {
            float t = acc[k] * i0 + b[cb + k];
            vo[k] = t > 0.f ? t : __expf(t) - 1.f;     // ELU (bf16 out: exp-1 ok)
        }
        #pragma unroll
        for (int k = 8; k < 16; ++k) {
            float t = acc[k] * i1 + b[cb + k];
            vo[k] = t > 0.f ? t : __expf(t) - 1.f;
        }
        unsigned po[8];
        #pragma unroll
        for (int k = 0; k < 8; ++k) po[k] = cvtpk(vo[2 * k], vo[2 * k + 1]);
        *(uint4*)(out + n * 64 + cb)     = make_uint4(po[0], po[1], po[2], po[3]);
        *(uint4*)(out + n * 64 + cb + 8) = make_uint4(po[4], po[5], po[6], po[7]);
    }
}

// ------- layer2 agg: 4 lanes/edge (16 slots), single head, fp32 out -------
__global__ __launch_bounds__(256) void agg_l2(const int* __restrict__ rowptr,
        const unsigned short* __restrict__ col, const unsigned short* __restrict__ hb,
        const float* __restrict__ ss, const float* __restrict__ sd,
        const float* __restrict__ b, float* __restrict__ out)
{
    int n = (blockIdx.x * 256 + threadIdx.x) >> 6;
    int lane = threadIdx.x & 63;
    if (n >= NN) return;
    const int sl = lane >> 2;
    const int j  = lane & 3;
    const int cb = j << 4;
    float sdn = sd[n];
    int r0 = rowptr[n], r1 = rowptr[n + 1];
    float acc[16];
    #pragma unroll
    for (int k = 0; k < 16; ++k) acc[k] = 0.f;
    float ds = 0.f;
    for (int i = r0; i < r1; i += 16) {
        int e = i + sl;
        bool v = e < r1;
        int a = (int)col[v ? e : r0];
        const unsigned short* hp = hb + a * 64 + cb;
        uint4 h0 = *(const uint4*)hp;
        uint4 h1 = *(const uint4*)(hp + 8);
        float sa = ss[a];
        float w = v ? __expf(LEAKY(sa + sdn)) : 0.f;
        acc[0]  += w * bflo(h0.x); acc[1]  += w * bfhi(h0.x);
        acc[2]  += w * bflo(h0.y); acc[3]  += w * bfhi(h0.y);
        acc[4]  += w * bflo(h0.z); acc[5]  += w * bfhi(h0.z);
        acc[6]  += w * bflo(h0.w); acc[7]  += w * bfhi(h0.w);
        acc[8]  += w * bflo(h1.x); acc[9]  += w * bfhi(h1.x);
        acc[10] += w * bflo(h1.y); acc[11] += w * bfhi(h1.y);
        acc[12] += w * bflo(h1.z); acc[13] += w * bfhi(h1.z);
        acc[14] += w * bflo(h1.w); acc[15] += w * bfhi(h1.w);
        ds += w;
    }
    #pragma unroll
    for (int m = 4; m <= 32; m <<= 1) {
        #pragma unroll
        for (int k = 0; k < 16; ++k) acc[k] += __shfl_xor(acc[k], m);
        ds += __shfl_xor(ds, m);
    }
    if (sl == 0) {
        float inv = 1.f / (ds + 1e-16f);
        float* op = out + n * 64 + cb;
        #pragma unroll
        for (int q = 0; q < 4; ++q) {
            float4 o;
            o.x = acc[q * 4 + 0] * inv + b[cb + q * 4 + 0];
            o.y = acc[q * 4 + 1] * inv + b[cb + q * 4 + 1];
            o.z = acc[q * 4 + 2] * inv + b[cb + q * 4 + 2];
            o.w = acc[q * 4 + 3] * inv + b[cb + q * 4 + 3];
            *(float4*)(op + q * 4) = o;
        }
    }
}

extern "C" void kernel_launch(void* const* d_in, const int* in_sizes, int n_in,
                              void* d_out, int out_size, void* d_ws, size_t ws_size,
                              hipStream_t stream)
{
    const float* x      = (const float*)d_in[0];
    const int*   ei     = (const int*)d_in[1];
    const float* W1     = (const float*)d_in[2];
    const float* a_src1 = (const float*)d_in[3];
    const float* a_dst1 = (const float*)d_in[4];
    const float* b1     = (const float*)d_in[5];
    const float* W2     = (const float*)d_in[6];
    const float* a_src2 = (const float*)d_in[7];
    const float* a_dst2 = (const float*)d_in[8];
    const float* b2     = (const float*)d_in[9];
    float* out = (float*)d_out;

    // workspace (16B-aligned blocks first)
    char* wp = (char*)d_ws;
    unsigned short* hb  = (unsigned short*)wp;  wp += (size_t)NN * 64 * 2;  // h1 then h2 (bf16)
    unsigned short* P1b = (unsigned short*)wp;  wp += (size_t)NN * 64 * 2;  // h2in (bf16)
    unsigned short* Bt1 = (unsigned short*)wp;  wp += (size_t)64 * 320 * 2; // W1^T bf16 padded
    unsigned short* Bt2 = (unsigned short*)wp;  wp += (size_t)64 * 64 * 2;  // W2^T bf16
    float* ss1 = (float*)wp;  wp += (size_t)NN * 8 * 4;
    float* sd1 = (float*)wp;  wp += (size_t)NN * 8 * 4;
    int* cnt    = (int*)wp;  wp += (size_t)NCNT * RPAD * 4;  // per-(chunk,range) counts
    unsigned char* rpre = (unsigned char*)wp;  wp += (size_t)NN * ECP;  // byte chunk-prefixes
    int* excl   = (int*)wp;  wp += (size_t)NN * 4;
    int* sums   = (int*)wp;  wp += 256 * 4;
    int* rowptr = (int*)wp;  wp += (size_t)(NN + 4) * 4;
    unsigned short* col = (unsigned short*)wp;  wp += (size_t)(NE + 8) * 2;
    unsigned char*  pos = (unsigned char*)wp;   wp += (size_t)NE;
    float* ss2 = ss1;                    // alias (layer1 logits dead in layer2)
    float* sd2 = ss1 + NN;

    const int NB = (NN + 1023) / 1024;   // 49

    k_count_prep<<<NCNT + NPB, 1024, 0, stream>>>(ei, cnt, pos, W1, W2, Bt1, Bt2);
    k_gemm_scan<<<NGB + NSB, 256, 0, stream>>>(
        x, Bt1, hb, a_src1, a_dst1, ss1, sd1, cnt, excl, sums, rpre);
    scan23<<<NB, 1024, 0, stream>>>(excl, sums, rowptr);
    scatter_k<<<(NE / 4 + 255) / 256, 256, 0, stream>>>(ei, rowptr, pos, rpre, col);

    agg_l1<<<(NN * 64 + 255) / 256, 256, 0, stream>>>(rowptr, col, hb, ss1, sd1, b1, P1b);
    gemm_l2<<<(NN + 63) / 64, 256, 0, stream>>>(P1b, Bt2, hb, a_src2, a_dst2, ss2, sd2);
    agg_l2<<<(NN * 64 + 255) / 256, 256, 0, stream>>>(rowptr, col, hb, ss2, sd2, b2, out);
}

// Round 11
// 218.030 us; speedup vs baseline: 1.1325x; 1.1325x over previous
//
#include <hip/hip_runtime.h>
#include <math.h>

#define NN 50000
#define NE 1000000
#define EC 31            // edge chunks, chunk = e >> CSH (31*32768 >= NE)
#define ECP 32           // rpre per-node stride (bytes)
#define CSH 15           // chunk size 32768
#define WR 8             // counter ranges
#define RNG 6250         // counters per range (8*6250 = NN)
#define RPAD 6272        // padded dump stride (ints), block-exclusive regions
#define NCNT (EC * WR)   // 248 count blocks
#define NPB 24           // prep blocks (24*1024 = 24576 = 64*320+64*64)
#define NGB 782          // gemm L1 blocks: ceil(NN/64)
#define NSB 196          // scan1 blocks (196*256 >= NN)

typedef __bf16 bf16x8 __attribute__((ext_vector_type(8)));
typedef float f32x4 __attribute__((ext_vector_type(4)));

__device__ inline unsigned short f2bf(float f) {          // fp32 -> bf16 RNE
    unsigned u = __float_as_uint(f);
    u += 0x7FFFu + ((u >> 16) & 1u);
    return (unsigned short)(u >> 16);
}
__device__ inline float bf2f(unsigned short s) {
    return __uint_as_float(((unsigned)s) << 16);
}
__device__ inline float bflo(unsigned r) { return __uint_as_float(r << 16); }
__device__ inline float bfhi(unsigned r) { return __uint_as_float(r & 0xffff0000u); }
__device__ inline unsigned cvtpk(float lo, float hi) {    // 2xf32 -> packed bf16 (RNE)
    unsigned u;
    asm("v_cvt_pk_bf16_f32 %0, %1, %2" : "=v"(u) : "v"(lo), "v"(hi));
    return u;
}

// ---- FUSED: CSR count (blocks [0,NCNT)) + weight prep (tail blocks). ----
__global__ __launch_bounds__(1024) void k_count_prep(
        const int* __restrict__ ei, int* __restrict__ cnt,
        unsigned char* __restrict__ pos,
        const float* __restrict__ W1, const float* __restrict__ W2,
        unsigned short* __restrict__ Bt1, unsigned short* __restrict__ Bt2)
{
    __shared__ __align__(16) int sm[RNG];          // 25000B (count blocks only)
    const int tid = threadIdx.x;
    const int bid = blockIdx.x;

    if (bid >= NCNT) {                             // ---- prep body ----
        int t = (bid - NCNT) * 1024 + tid;
        if (t < 64 * 320) {
            int c = t / 320, k = t % 320;
            Bt1[t] = (k < 300) ? f2bf(W1[k * 64 + c]) : (unsigned short)0;
        } else {
            int i = t - 64 * 320;
            int c = i >> 6, k = i & 63;
            Bt2[i] = f2bf(W2[k * 64 + c]);
        }
        return;
    }
    // ---- count body: chunk c, range w ----
    const int c = bid >> 3, w = bid & 7;
    const int lo = w * RNG;
    for (int j = tid; j < RNG; j += 1024) sm[j] = 0;
    __syncthreads();
    const int base = c << CSH;
    #pragma unroll
    for (int it = 0; it < (1 << CSH) / 4096; ++it) {
        int e = base + (it * 1024 + tid) * 4;
        if (e < NE) {                               // NE%4==0 -> whole int4 valid
            int4 d = *(const int4*)(ei + NE + e);
            unsigned t0 = (unsigned)(d.x - lo), t1 = (unsigned)(d.y - lo);
            unsigned t2 = (unsigned)(d.z - lo), t3 = (unsigned)(d.w - lo);
            if (t0 < RNG) pos[e]     = (unsigned char)atomicAdd(&sm[t0], 1);
            if (t1 < RNG) pos[e + 1] = (unsigned char)atomicAdd(&sm[t1], 1);
            if (t2 < RNG) pos[e + 2] = (unsigned char)atomicAdd(&sm[t2], 1);
            if (t3 < RNG) pos[e + 3] = (unsigned char)atomicAdd(&sm[t3], 1);
        }
    }
    __syncthreads();
    int* dstp = cnt + (size_t)bid * RPAD;          // exclusive region
    for (int j = tid; j < RNG; j += 1024) dstp[j] = sm[j];
}

// ---- FUSED: L1 MFMA GEMM (blocks [0,NGB)) + scan1 (tail blocks).
//      BK=64, cvt_pk staging (verified bit-identical absmax in R9). ----
__global__ __launch_bounds__(256) void k_gemm_scan(
        const float* __restrict__ A, const unsigned short* __restrict__ Bt,
        unsigned short* __restrict__ hb,
        const float* __restrict__ asrc, const float* __restrict__ adst,
        float* __restrict__ ss, float* __restrict__ sd,
        const int* __restrict__ cnt, int* __restrict__ excl,
        int* __restrict__ sums, unsigned char* __restrict__ rpre)
{
    __shared__ __align__(16) unsigned short lds[9216];   // 18432B
    const int tid = threadIdx.x;
    const int bid = blockIdx.x;

    if (bid >= NGB) {
        // ---------------- scan1 body (256 elements/block) ----------------
        const int sb = bid - NGB;
        int i = sb * 256 + tid;
        int v = 0;
        if (i < NN) {
            int w8 = i / RNG;                    // counter range 0..7
            int j = i - w8 * RNG;
            int run = 0;
            unsigned pk[ECP / 4];
            #pragma unroll
            for (int q = 0; q < ECP / 4; ++q) pk[q] = 0;
            #pragma unroll
            for (int cc = 0; cc < EC; ++cc) {
                pk[cc >> 2] |= ((unsigned)run & 0xffu) << ((cc & 3) * 8);
                run += cnt[(size_t)(cc * 8 + w8) * RPAD + j];
            }
            v = run;
            *(uint4*)(rpre + (size_t)i * ECP)      = make_uint4(pk[0], pk[1], pk[2], pk[3]);
            *(uint4*)(rpre + (size_t)i * ECP + 16) = make_uint4(pk[4], pk[5], pk[6], pk[7]);
        }
        int* buf = (int*)lds;
        buf[tid] = v;
        __syncthreads();
        #pragma unroll
        for (int off = 1; off < 256; off <<= 1) {
            int t = (tid >= off) ? buf[tid - off] : 0;
            __syncthreads();
            buf[tid] += t;
            __syncthreads();
        }
        if (i < NN) excl[i] = buf[tid] - v;
        if (tid == 255) sums[sb] = buf[255];
        return;
    }

    // ---------------- gemm body (HEADS=8, A fp32, K=300, BK=64, KT=5) ----------------
    const int row0 = bid * 64;
    const int lane = tid & 63, w = tid >> 6;
    const int quad = lane >> 4, mm = lane & 15;
    const int sr = tid >> 2, q16 = (tid & 3) * 16;
    const int gsr = row0 + sr;
    const int K = 300, M = NN;

    f32x4 acc[4];
    #pragma unroll
    for (int i = 0; i < 4; ++i) acc[i] = (f32x4){0.f, 0.f, 0.f, 0.f};

    for (int kt = 0; kt < 5; ++kt) {
        const int k0 = kt * 64;
        int4 a0 = {0, 0, 0, 0}, a1 = {0, 0, 0, 0};
        if (gsr < M) {
            const float* ap = A + (size_t)gsr * K + k0 + q16;
            if (k0 + q16 + 15 < K) {
                float4 v0 = *(const float4*)ap;
                float4 v1 = *(const float4*)(ap + 4);
                float4 v2 = *(const float4*)(ap + 8);
                float4 v3 = *(const float4*)(ap + 12);
                a0.x = (int)cvtpk(v0.x, v0.y); a0.y = (int)cvtpk(v0.z, v0.w);
                a0.z = (int)cvtpk(v1.x, v1.y); a0.w = (int)cvtpk(v1.z, v1.w);
                a1.x = (int)cvtpk(v2.x, v2.y); a1.y = (int)cvtpk(v2.z, v2.w);
                a1.z = (int)cvtpk(v3.x, v3.y); a1.w = (int)cvtpk(v3.z, v3.w);
            } else {
                unsigned short* u0 = (unsigned short*)&a0;
                unsigned short* u1 = (unsigned short*)&a1;
                #pragma unroll
                for (int j = 0; j < 8; ++j)
                    u0[j] = (k0 + q16 + j < K) ? f2bf(ap[j]) : (unsigned short)0;
                #pragma unroll
                for (int j = 0; j < 8; ++j)
                    u1[j] = (k0 + q16 + 8 + j < K) ? f2bf(ap[8 + j]) : (unsigned short)0;
            }
        }
        *(int4*)(lds + sr * 72 + q16)     = a0;
        *(int4*)(lds + sr * 72 + q16 + 8) = a1;
        *(int4*)(lds + 4608 + sr * 72 + q16) =
            *(const int4*)(Bt + (size_t)sr * 320 + k0 + q16);
        *(int4*)(lds + 4608 + sr * 72 + q16 + 8) =
            *(const int4*)(Bt + (size_t)sr * 320 + k0 + q16 + 8);
        __syncthreads();
        bf16x8 af0 = *(const bf16x8*)(lds + (w * 16 + mm) * 72 + quad * 8);
        bf16x8 af1 = *(const bf16x8*)(lds + (w * 16 + mm) * 72 + 32 + quad * 8);
        #pragma unroll
        for (int nt = 0; nt < 4; ++nt) {
            bf16x8 b0 = *(const bf16x8*)(lds + 4608 + (nt * 16 + mm) * 72 + quad * 8);
            bf16x8 b1 = *(const bf16x8*)(lds + 4608 + (nt * 16 + mm) * 72 + 32 + quad * 8);
            acc[nt] = __builtin_amdgcn_mfma_f32_16x16x32_bf16(af0, b0, acc[nt], 0, 0, 0);
            acc[nt] = __builtin_amdgcn_mfma_f32_16x16x32_bf16(af1, b1, acc[nt], 0, 0, 0);
        }
        __syncthreads();
    }
    // epilogue: C (col=lane&15, row=quad*4+reg) -> LDS bf16 tile (stride 72)
    #pragma unroll
    for (int nt = 0; nt < 4; ++nt)
        #pragma unroll
        for (int reg = 0; reg < 4; ++reg)
            lds[w * 1152 + (quad * 4 + reg) * 72 + nt * 16 + mm] = f2bf(acc[nt][reg]);
    __syncthreads();
    const int cg = (tid & 3) * 16;
    const unsigned short* crow = lds + (sr >> 4) * 1152 + (sr & 15) * 72;
    if (gsr < M) {
        *(int4*)(hb + (size_t)gsr * 64 + cg)     = *(const int4*)(crow + cg);
        *(int4*)(hb + (size_t)gsr * 64 + cg + 8) = *(const int4*)(crow + cg + 8);
    }
    #pragma unroll
    for (int hh = 0; hh < 2; ++hh) {
        int hd = (tid & 3) + hh * 4;
        float pss = 0.f, psd = 0.f;
        #pragma unroll
        for (int c = 0; c < 8; ++c) {
            float hv = bf2f(crow[hd * 8 + c]);
            pss += hv * asrc[hd * 8 + c];
            psd += hv * adst[hd * 8 + c];
        }
        if (gsr < M) { ss[gsr * 8 + hd] = pss; sd[gsr * 8 + hd] = psd; }
    }
}

// ---- MFMA GEMM layer 2 (A bf16, K=64 single tile, 1 barrier pair) ----
__global__ __launch_bounds__(256) void gemm_l2(const unsigned short* __restrict__ A,
        const unsigned short* __restrict__ Bt, unsigned short* __restrict__ hb,
        const float* __restrict__ asrc, const float* __restrict__ adst,
        float* __restrict__ ss, float* __restrict__ sd)
{
    __shared__ __align__(16) unsigned short lds[9216];
    const int tid  = threadIdx.x;
    const int row0 = blockIdx.x * 64;
    const int lane = tid & 63, w = tid >> 6;
    const int quad = lane >> 4, mm = lane & 15;
    const int sr = tid >> 2, q16 = (tid & 3) * 16;
    const int gsr = row0 + sr;

    f32x4 acc[4];
    #pragma unroll
    for (int i = 0; i < 4; ++i) acc[i] = (f32x4){0.f, 0.f, 0.f, 0.f};

    int4 a0 = {0, 0, 0, 0}, a1 = {0, 0, 0, 0};
    if (gsr < NN) {
        a0 = *(const int4*)(A + (size_t)gsr * 64 + q16);
        a1 = *(const int4*)(A + (size_t)gsr * 64 + q16 + 8);
    }
    *(int4*)(lds + sr * 72 + q16)     = a0;
    *(int4*)(lds + sr * 72 + q16 + 8) = a1;
    *(int4*)(lds + 4608 + sr * 72 + q16)     = *(const int4*)(Bt + sr * 64 + q16);
    *(int4*)(lds + 4608 + sr * 72 + q16 + 8) = *(const int4*)(Bt + sr * 64 + q16 + 8);
    __syncthreads();
    bf16x8 af0 = *(const bf16x8*)(lds + (w * 16 + mm) * 72 + quad * 8);
    bf16x8 af1 = *(const bf16x8*)(lds + (w * 16 + mm) * 72 + 32 + quad * 8);
    #pragma unroll
    for (int nt = 0; nt < 4; ++nt) {
        bf16x8 b0 = *(const bf16x8*)(lds + 4608 + (nt * 16 + mm) * 72 + quad * 8);
        bf16x8 b1 = *(const bf16x8*)(lds + 4608 + (nt * 16 + mm) * 72 + 32 + quad * 8);
        acc[nt] = __builtin_amdgcn_mfma_f32_16x16x32_bf16(af0, b0, acc[nt], 0, 0, 0);
        acc[nt] = __builtin_amdgcn_mfma_f32_16x16x32_bf16(af1, b1, acc[nt], 0, 0, 0);
    }
    __syncthreads();
    #pragma unroll
    for (int nt = 0; nt < 4; ++nt)
        #pragma unroll
        for (int reg = 0; reg < 4; ++reg)
            lds[w * 1152 + (quad * 4 + reg) * 72 + nt * 16 + mm] = f2bf(acc[nt][reg]);
    __syncthreads();
    const int cg = (tid & 3) * 16;
    const unsigned short* crow = lds + (sr >> 4) * 1152 + (sr & 15) * 72;
    if (gsr < NN) {
        *(int4*)(hb + (size_t)gsr * 64 + cg)     = *(const int4*)(crow + cg);
        *(int4*)(hb + (size_t)gsr * 64 + cg + 8) = *(const int4*)(crow + cg + 8);
    }
    int p = tid & 3;
    float pss = 0.f, psd = 0.f;
    #pragma unroll
    for (int c = 0; c < 16; ++c) {
        float hv = bf2f(crow[p * 16 + c]);
        pss += hv * asrc[p * 16 + c];
        psd += hv * adst[p * 16 + c];
    }
    pss += __shfl_xor(pss, 1); psd += __shfl_xor(psd, 1);
    pss += __shfl_xor(pss, 2); psd += __shfl_xor(psd, 2);
    if (p == 0 && gsr < NN) { ss[gsr] = pss; sd[gsr] = psd; }
}

// ------------- scan stage 2+3: each block scans 196 sums redundantly -------------
__global__ __launch_bounds__(1024) void scan23(const int* __restrict__ excl,
        const int* __restrict__ sums, int* __restrict__ rowptr)
{
    int blk = (int)blockIdx.x * 4;                  // 1024-block spans 4 scan1 blocks
    int off = 0;
    for (int j = 0; j < blk; ++j) off += sums[j];   // uniform scalar loop
    int sub = (threadIdx.x >> 8);                   // which 256-group
    for (int j = 0; j < sub; ++j) off += sums[blk + j];
    int i = (int)blockIdx.x * 1024 + threadIdx.x;
    if (i < NN) rowptr[i] = excl[i] + off;
    if (i == 0) rowptr[NN] = NE;
}

// ------ CSR scatter: slot = rowptr[d] + rpre[d][chunk(e)] + pos[e] ------
__global__ __launch_bounds__(256) void scatter_k(const int* __restrict__ ei,
        const int* __restrict__ rowptr, const unsigned char* __restrict__ pos,
        const unsigned char* __restrict__ rpre, unsigned short* __restrict__ col)
{
    int e = (blockIdx.x * 256 + threadIdx.x) * 4;   // NE % 4 == 0
    if (e >= NE) return;
    int c = e >> CSH;                               // chunk uniform over the int4
    int4 s = *(const int4*)(ei + e);
    int4 d = *(const int4*)(ei + NE + e);
    uchar4 p = *(const uchar4*)(pos + e);
    int r0 = rowptr[d.x] + (int)rpre[(d.x << 5) + c] + p.x;
    int r1 = rowptr[d.y] + (int)rpre[(d.y << 5) + c] + p.y;
    int r2 = rowptr[d.z] + (int)rpre[(d.z << 5) + c] + p.z;
    int r3 = rowptr[d.w] + (int)rpre[(d.w << 5) + c] + p.w;
    col[r0] = (unsigned short)s.x;
    col[r1] = (unsigned short)s.y;
    col[r2] = (unsigned short)s.z;
    col[r3] = (unsigned short)s.w;
}

#define LEAKY(s) ((s) > 0.f ? (s) : 0.2f * (s))

// ------- layer1 agg (R8-verified form): wave/node, 32 edges in flight -------
__global__ __launch_bounds__(256) void agg_l1(const int* __restrict__ rowptr,
        const unsigned short* __restrict__ col, const unsigned short* __restrict__ hb,
        const float* __restrict__ ss, const float* __restrict__ sd,
        const float* __restrict__ b, unsigned short* __restrict__ out)
{
    int n = (blockIdx.x * 256 + threadIdx.x) >> 6;
    int lane = threadIdx.x & 63;
    if (n >= NN) return;
    const int es = lane >> 4;            // edge slot 0..3
    const int cg = (lane & 15) << 2;     // channel group base
    const int hd = cg >> 3;              // head
    float sdst = sd[n * 8 + hd];
    int r0 = rowptr[n], r1 = rowptr[n + 1];
    f32x4 acc = {0.f, 0.f, 0.f, 0.f};
    float dsum = 0.f;
    for (int i = r0; i < r1; i += 32) {
        int av[8]; bool vv[8];
        #pragma unroll
        for (int u = 0; u < 8; ++u) {
            int e = i + u * 4 + es;
            vv[u] = e < r1;
            av[u] = (int)col[vv[u] ? e : r0];
        }
        uint2 rr[8]; float sv[8];
        #pragma unroll
        for (int u = 0; u < 8; ++u) {
            rr[u] = *(const uint2*)(hb + av[u] * 64 + cg);
            sv[u] = ss[av[u] * 8 + hd];
        }
        #pragma unroll
        for (int u = 0; u < 8; ++u) {
            float wv = vv[u] ? __expf(LEAKY(sv[u] + sdst)) : 0.f;
            acc[0] += wv * bflo(rr[u].x);
            acc[1] += wv * bfhi(rr[u].x);
            acc[2] += wv * bflo(rr[u].y);
            acc[3] += wv * bfhi(rr[u].y);
            dsum += wv;
        }
    }
    #pragma unroll
    for (int m = 16; m <= 32; m <<= 1) {
        acc[0] += __shfl_xor(acc[0], m); acc[1] += __shfl_xor(acc[1], m);
        acc[2] += __shfl_xor(acc[2], m); acc[3] += __shfl_xor(acc[3], m);
        dsum += __shfl_xor(dsum, m);
    }
    if (es == 0) {
        float inv = 1.f / (dsum + 1e-16f);
        float v0 = acc[0] * inv + b[cg + 0]; v0 = v0 > 0.f ? v0 : __expf(v0) - 1.f;
        float v1 = acc[1] * inv + b[cg + 1]; v1 = v1 > 0.f ? v1 : __expf(v1) - 1.f;
        float v2 = acc[2] * inv + b[cg + 2]; v2 = v2 > 0.f ? v2 : __expf(v2) - 1.f;
        float v3 = acc[3] * inv + b[cg + 3]; v3 = v3 > 0.f ? v3 : __expf(v3) - 1.f;
        unsigned o01 = (unsigned)f2bf(v0) | ((unsigned)f2bf(v1) << 16);
        unsigned o23 = (unsigned)f2bf(v2) | ((unsigned)f2bf(v3) << 16);
        *(uint2*)(out + n * 64 + cg) = make_uint2(o01, o23);
    }
}

// ------- layer2 agg (R8-verified form): wave/node, 32 edges in flight, fp32 out -------
__global__ __launch_bounds__(256) void agg_l2(const int* __restrict__ rowptr,
        const unsigned short* __restrict__ col, const unsigned short* __restrict__ hb,
        const float* __restrict__ ss, const float* __restrict__ sd,
        const float* __restrict__ b, float* __restrict__ out)
{
    int n = (blockIdx.x * 256 + threadIdx.x) >> 6;
    int lane = threadIdx.x & 63;
    if (n >= NN) return;
    const int es = lane >> 4;
    const int cg = (lane & 15) << 2;
    float sdst = sd[n];
    int r0 = rowptr[n], r1 = rowptr[n + 1];
    f32x4 acc = {0.f, 0.f, 0.f, 0.f};
    float dsum = 0.f;
    for (int i = r0; i < r1; i += 32) {
        int av[8]; bool vv[8];
        #pragma unroll
        for (int u = 0; u < 8; ++u) {
            int e = i + u * 4 + es;
            vv[u] = e < r1;
            av[u] = (int)col[vv[u] ? e : r0];
        }
        uint2 rr[8]; float sv[8];
        #pragma unroll
        for (int u = 0; u < 8; ++u) {
            rr[u] = *(const uint2*)(hb + av[u] * 64 + cg);
            sv[u] = ss[av[u]];
        }
        #pragma unroll
        for (int u = 0; u < 8; ++u) {
            float wv = vv[u] ? __expf(LEAKY(sv[u] + sdst)) : 0.f;
            acc[0] += wv * bflo(rr[u].x);
            acc[1] += wv * bfhi(rr[u].x);
            acc[2] += wv * bflo(rr[u].y);
            acc[3] += wv * bfhi(rr[u].y);
            dsum += wv;
        }
    }
    #pragma unroll
    for (int m = 16; m <= 32; m <<= 1) {
        acc[0] += __shfl_xor(acc[0], m); acc[1] += __shfl_xor(acc[1], m);
        acc[2] += __shfl_xor(acc[2], m); acc[3] += __shfl_xor(acc[3], m);
        dsum += __shfl_xor(dsum, m);
    }
    if (es == 0) {
        float inv = 1.f / (dsum + 1e-16f);
        float4 o;
        o.x = acc[0] * inv + b[cg + 0];
        o.y = acc[1] * inv + b[cg + 1];
        o.z = acc[2] * inv + b[cg + 2];
        o.w = acc[3] * inv + b[cg + 3];
        *(float4*)(out + n * 64 + cg) = o;
    }
}

extern "C" void kernel_launch(void* const* d_in, const int* in_sizes, int n_in,
                              void* d_out, int out_size, void* d_ws, size_t ws_size,
                              hipStream_t stream)
{
    const float* x      = (const float*)d_in[0];
    const int*   ei     = (const int*)d_in[1];
    const float* W1     = (const float*)d_in[2];
    const float* a_src1 = (const float*)d_in[3];
    const float* a_dst1 = (const float*)d_in[4];
    const float* b1     = (const float*)d_in[5];
    const float* W2     = (const float*)d_in[6];
    const float* a_src2 = (const float*)d_in[7];
    const float* a_dst2 = (const float*)d_in[8];
    const float* b2     = (const float*)d_in[9];
    float* out = (float*)d_out;

    // workspace (16B-aligned blocks first)
    char* wp = (char*)d_ws;
    unsigned short* hb  = (unsigned short*)wp;  wp += (size_t)NN * 64 * 2;  // h1 then h2 (bf16)
    unsigned short* P1b = (unsigned short*)wp;  wp += (size_t)NN * 64 * 2;  // h2in (bf16)
    unsigned short* Bt1 = (unsigned short*)wp;  wp += (size_t)64 * 320 * 2; // W1^T bf16 padded
    unsigned short* Bt2 = (unsigned short*)wp;  wp += (size_t)64 * 64 * 2;  // W2^T bf16
    float* ss1 = (float*)wp;  wp += (size_t)NN * 8 * 4;
    float* sd1 = (float*)wp;  wp += (size_t)NN * 8 * 4;
    int* cnt    = (int*)wp;  wp += (size_t)NCNT * RPAD * 4;  // per-(chunk,range) counts
    unsigned char* rpre = (unsigned char*)wp;  wp += (size_t)NN * ECP;  // byte chunk-prefixes
    int* excl   = (int*)wp;  wp += (size_t)NN * 4;
    int* sums   = (int*)wp;  wp += 256 * 4;
    int* rowptr = (int*)wp;  wp += (size_t)(NN + 4) * 4;
    unsigned short* col = (unsigned short*)wp;  wp += (size_t)(NE + 8) * 2;
    unsigned char*  pos = (unsigned char*)wp;   wp += (size_t)NE;
    float* ss2 = ss1;                    // alias (layer1 logits dead in layer2)
    float* sd2 = ss1 + NN;

    const int NB = (NN + 1023) / 1024;   // 49

    k_count_prep<<<NCNT + NPB, 1024, 0, stream>>>(ei, cnt, pos, W1, W2, Bt1, Bt2);
    k_gemm_scan<<<NGB + NSB, 256, 0, stream>>>(
        x, Bt1, hb, a_src1, a_dst1, ss1, sd1, cnt, excl, sums, rpre);
    scan23<<<NB, 1024, 0, stream>>>(excl, sums, rowptr);
    scatter_k<<<(NE / 4 + 255) / 256, 256, 0, stream>>>(ei, rowptr, pos, rpre, col);

    agg_l1<<<(NN * 64 + 255) / 256, 256, 0, stream>>>(rowptr, col, hb, ss1, sd1, b1, P1b);
    gemm_l2<<<(NN + 63) / 64, 256, 0, stream>>>(P1b, Bt2, hb, a_src2, a_dst2, ss2, sd2);
    agg_l2<<<(NN * 64 + 255) / 256, 256, 0, stream>>>(rowptr, col, hb, ss2, sd2, b2, out);
}